// Round 1
// baseline (40.826 us; speedup 1.0000x reference)
//
#include <hip/hip_runtime.h>

// SpecAugment: out[b,m,t] = (freq_masked(b,m) || time_masked(b,t)) ? 0 : in[b,m,t]
// B=64, M=128, T=4000, fp32. Pure streaming, memory-bound.

constexpr int B_DIM = 64;
constexpr int M_DIM = 128;
constexpr int T_DIM = 4000;
constexpr int T4 = T_DIM / 4;                       // 1000 float4 per row
constexpr int TOTAL4 = B_DIM * M_DIM * T4;          // 8,192,000 float4s

__global__ __launch_bounds__(256) void specaug_kernel(
    const float4* __restrict__ in,
    const int*    __restrict__ f,   // [2][B]
    const int*    __restrict__ f0,  // [2][B]
    const int*    __restrict__ t,   // [2][B]
    const int*    __restrict__ t0,  // [2][B]
    float4*       __restrict__ out)
{
    const int stride = gridDim.x * blockDim.x;
    for (int g = blockIdx.x * blockDim.x + threadIdx.x; g < TOTAL4; g += stride) {
        const int row = g / T4;            // compiler turns into magic-mul
        const int t4  = g - row * T4;
        const int b   = row >> 7;          // row / 128
        const int m   = row & 127;         // row % 128

        // frequency mask (uniform over the whole row)
        const int fA0 = f0[b],         fA = f[b];
        const int fB0 = f0[B_DIM + b], fB = f[B_DIM + b];
        const bool fm = ((unsigned)(m - fA0) < (unsigned)fA) |
                        ((unsigned)(m - fB0) < (unsigned)fB);

        float4 v;
        if (fm) {
            // whole row masked: skip the input read
            v = make_float4(0.f, 0.f, 0.f, 0.f);
        } else {
            v = in[g];
            const int tA0 = t0[b],         tA = t[b];
            const int tB0 = t0[B_DIM + b], tB = t[B_DIM + b];
            const int tbase = t4 * 4;
            float* vp = &v.x;
            #pragma unroll
            for (int j = 0; j < 4; ++j) {
                const int tt = tbase + j;
                const bool tm = ((unsigned)(tt - tA0) < (unsigned)tA) |
                                ((unsigned)(tt - tB0) < (unsigned)tB);
                if (tm) vp[j] = 0.f;
            }
        }
        out[g] = v;
    }
}

extern "C" void kernel_launch(void* const* d_in, const int* in_sizes, int n_in,
                              void* d_out, int out_size, void* d_ws, size_t ws_size,
                              hipStream_t stream) {
    const float4* in = (const float4*)d_in[0];
    const int*    f  = (const int*)d_in[1];
    const int*    f0 = (const int*)d_in[2];
    const int*    t  = (const int*)d_in[3];
    const int*    t0 = (const int*)d_in[4];
    float4*       out = (float4*)d_out;

    // memory-bound: cap grid at 2048 blocks (256 CU x 8 blocks/CU), grid-stride
    const int block = 256;
    const int grid  = 2048;
    specaug_kernel<<<grid, block, 0, stream>>>(in, f, f0, t, t0, out);
}